// Round 1
// baseline (1440.193 us; speedup 1.0000x reference)
//
#include <hip/hip_runtime.h>

#define EMB 768
#define HEADS 8
#define HD 96
#define BB 4
#define NN 2048
#define BN (BB*NN)   // 8192

// ---------------------------------------------------------------------------
// Kernel 1: fused QKV projection. out = x @ W + b, written head-split
// [B][H][N][HD]. grid = (BN/64, EMB/64, 3), block = 256.
// ---------------------------------------------------------------------------
__global__ __launch_bounds__(256) void proj_qkv(
    const float* __restrict__ x,
    const float* __restrict__ Wq, const float* __restrict__ bq,
    const float* __restrict__ Wk, const float* __restrict__ bk,
    const float* __restrict__ Wv, const float* __restrict__ bv,
    float* __restrict__ Q, float* __restrict__ K, float* __restrict__ V)
{
    const float* W; const float* bias; float* out;
    if (blockIdx.z == 0)      { W = Wq; bias = bq; out = Q; }
    else if (blockIdx.z == 1) { W = Wk; bias = bk; out = K; }
    else                      { W = Wv; bias = bv; out = V; }

    __shared__ float As[16][68];  // x tile, transposed: As[kk][m]
    __shared__ float Bs[16][68];  // W tile: Bs[kk][n]

    const int tid = threadIdx.x;
    const int tx = tid & 15, ty = tid >> 4;
    const int mbase = blockIdx.x * 64;
    const int nbase = blockIdx.y * 64;

    // loader indices
    const int lr  = tid >> 2;   // 0..63 : A row
    const int lq  = tid & 3;    // 0..3  : float4 slot in 16-wide k
    const int lkk = tid >> 4;   // 0..15 : B k-row
    const int lj  = tid & 15;   // 0..15 : B float4 col

    float acc[4][4] = {};

    for (int k0 = 0; k0 < EMB; k0 += 16) {
        float4 a = *(const float4*)&x[(size_t)(mbase + lr) * EMB + k0 + lq * 4];
        float4 b = *(const float4*)&W[(size_t)(k0 + lkk) * EMB + nbase + lj * 4];
        __syncthreads();   // previous iteration's LDS reads done
        As[lq*4+0][lr] = a.x; As[lq*4+1][lr] = a.y;
        As[lq*4+2][lr] = a.z; As[lq*4+3][lr] = a.w;
        *(float4*)&Bs[lkk][lj*4] = b;
        __syncthreads();
        #pragma unroll
        for (int kk = 0; kk < 16; ++kk) {
            float4 av = *(const float4*)&As[kk][ty*4];
            float4 bv4 = *(const float4*)&Bs[kk][tx*4];
            float am[4] = {av.x, av.y, av.z, av.w};
            float bm[4] = {bv4.x, bv4.y, bv4.z, bv4.w};
            #pragma unroll
            for (int i = 0; i < 4; ++i)
                #pragma unroll
                for (int j = 0; j < 4; ++j)
                    acc[i][j] += am[i] * bm[j];
        }
    }

    #pragma unroll
    for (int j = 0; j < 4; ++j) {
        const int e = nbase + tx*4 + j;
        const float bvv = bias[e];
        const int h = e / HD, d = e % HD;
        #pragma unroll
        for (int i = 0; i < 4; ++i) {
            const int row = mbase + ty*4 + i;
            const int bb = row >> 11, n = row & (NN - 1);
            out[(((size_t)(bb * HEADS + h)) * NN + n) * HD + d] = acc[i][j] + bvv;
        }
    }
}

// ---------------------------------------------------------------------------
// Kernel 2: flash-style attention, fp32. One block = one (b,h) x 32 q-rows.
// softmax(energy) / sqrt(HD), applied to V.  grid = (NN/32, B*H), block 256.
// ---------------------------------------------------------------------------
__global__ __launch_bounds__(256) void attn_fwd(
    const float* __restrict__ Q, const float* __restrict__ K,
    const float* __restrict__ V, float* __restrict__ AO)
{
    __shared__ float Qs[HD][36];    // Q tile transposed: Qs[d][r], r<32
    __shared__ float KVs[HD][68];   // K tile transposed Ks[d][r], r<64; reused for V [64][100]
    __shared__ float Ps[32][68];    // probability tile

    const int tid = threadIdx.x;
    const int tx = tid & 15, ty = tid >> 4;
    const int qbase = blockIdx.x * 32;
    const int bh = blockIdx.y;

    const float* Qp = Q + (size_t)bh * NN * HD;
    const float* Kp = K + (size_t)bh * NN * HD;
    const float* Vp = V + (size_t)bh * NN * HD;

    // load Q tile (32 x 96), store transposed
    {
        const int r = tid >> 3;      // 0..31
        const int seg = tid & 7;     // 0..7, 12 floats each
        const float* src = &Qp[(size_t)(qbase + r) * HD + seg * 12];
        #pragma unroll
        for (int c = 0; c < 3; ++c) {
            float4 v = *(const float4*)&src[c * 4];
            const int d0 = seg * 12 + c * 4;
            Qs[d0+0][r] = v.x; Qs[d0+1][r] = v.y;
            Qs[d0+2][r] = v.z; Qs[d0+3][r] = v.w;
        }
    }

    const int q0 = ty * 2;     // 2 q-rows per thread
    const int k0 = tx * 4;     // 4 k-cols per thread (S tile)
    const int c0 = tx * 6;     // 6 d-cols per thread (O tile)

    float m[2] = {-1e30f, -1e30f};
    float l[2] = {0.f, 0.f};
    float o[2][6] = {};

    for (int kt = 0; kt < NN / 64; ++kt) {
        const int kb = kt * 64;

        __syncthreads();  // prev iter's KVs/Ps reads done (also covers Q-load on iter 0... Q read is after next sync)
        // load K tile (64 x 96) transposed into KVs[d][r]
        {
            const int r = tid >> 2;    // 0..63
            const int seg = tid & 3;   // 0..3, 24 floats each
            const float* src = &Kp[(size_t)(kb + r) * HD + seg * 24];
            #pragma unroll
            for (int c = 0; c < 6; ++c) {
                float4 v = *(const float4*)&src[c * 4];
                const int d0 = seg * 24 + c * 4;
                KVs[d0+0][r] = v.x; KVs[d0+1][r] = v.y;
                KVs[d0+2][r] = v.z; KVs[d0+3][r] = v.w;
            }
        }
        __syncthreads();

        // S = Q K^T  (2x4 per thread)
        float s[2][4] = {};
        #pragma unroll 4
        for (int d = 0; d < HD; ++d) {
            float2 qa = *(const float2*)&Qs[d][q0];
            float4 kv = *(const float4*)&KVs[d][k0];
            s[0][0] += qa.x * kv.x; s[0][1] += qa.x * kv.y;
            s[0][2] += qa.x * kv.z; s[0][3] += qa.x * kv.w;
            s[1][0] += qa.y * kv.x; s[1][1] += qa.y * kv.y;
            s[1][2] += qa.y * kv.z; s[1][3] += qa.y * kv.w;
        }

        // online softmax update (per q-row, reduced over the 16 tx lanes)
        float sc[2];
        #pragma unroll
        for (int i = 0; i < 2; ++i) {
            float tm = fmaxf(fmaxf(s[i][0], s[i][1]), fmaxf(s[i][2], s[i][3]));
            #pragma unroll
            for (int off = 1; off < 16; off <<= 1)
                tm = fmaxf(tm, __shfl_xor(tm, off));
            const float mn = fmaxf(m[i], tm);
            sc[i] = __expf(m[i] - mn);
            float ps = 0.f;
            #pragma unroll
            for (int j = 0; j < 4; ++j) {
                const float p = __expf(s[i][j] - mn);
                s[i][j] = p;
                ps += p;
            }
            #pragma unroll
            for (int off = 1; off < 16; off <<= 1)
                ps += __shfl_xor(ps, off);
            l[i] = l[i] * sc[i] + ps;
            m[i] = mn;
            #pragma unroll
            for (int c = 0; c < 6; ++c) o[i][c] *= sc[i];
        }

        __syncthreads();  // all K reads done; KVs free for V

        // stage P, load V tile (row-major [64][100]) into the same buffer
        *(float4*)&Ps[q0+0][k0] = make_float4(s[0][0], s[0][1], s[0][2], s[0][3]);
        *(float4*)&Ps[q0+1][k0] = make_float4(s[1][0], s[1][1], s[1][2], s[1][3]);
        float* Vb = &KVs[0][0];
        {
            const int r = tid >> 2;
            const int seg = tid & 3;
            const float* src = &Vp[(size_t)(kb + r) * HD + seg * 24];
            #pragma unroll
            for (int c = 0; c < 6; ++c) {
                float4 v = *(const float4*)&src[c * 4];
                *(float4*)&Vb[r * 100 + seg * 24 + c * 4] = v;
            }
        }
        __syncthreads();

        // O += P @ V   (2 rows x 6 cols per thread)
        #pragma unroll 4
        for (int k = 0; k < 64; ++k) {
            const float p0 = Ps[q0+0][k];
            const float p1 = Ps[q0+1][k];
            const float* vrow = &Vb[k * 100 + c0];
            float2 v0 = *(const float2*)&vrow[0];
            float2 v1 = *(const float2*)&vrow[2];
            float2 v2 = *(const float2*)&vrow[4];
            o[0][0] += p0 * v0.x; o[0][1] += p0 * v0.y;
            o[0][2] += p0 * v1.x; o[0][3] += p0 * v1.y;
            o[0][4] += p0 * v2.x; o[0][5] += p0 * v2.y;
            o[1][0] += p1 * v0.x; o[1][1] += p1 * v0.y;
            o[1][2] += p1 * v1.x; o[1][3] += p1 * v1.y;
            o[1][4] += p1 * v2.x; o[1][5] += p1 * v2.y;
        }
    }

    // epilogue: divide by l (softmax denom) and by sqrt(HD) (post-softmax per ref)
    const float isq = 0.10206207261596577f;  // 1/sqrt(96)
    #pragma unroll
    for (int i = 0; i < 2; ++i) {
        const float scale = isq / l[i];
        float* dst = &AO[((size_t)bh * NN + qbase + q0 + i) * HD + c0];
        #pragma unroll
        for (int c = 0; c < 6; ++c) dst[c] = o[i][c] * scale;
    }
}

// ---------------------------------------------------------------------------
// Kernel 3: output projection: out = AO(head-merged) @ Wo + bo.
// grid = (BN/64, EMB/64), block 256.
// ---------------------------------------------------------------------------
__global__ __launch_bounds__(256) void proj_out_k(
    const float* __restrict__ AO, const float* __restrict__ Wo,
    const float* __restrict__ bo, float* __restrict__ out)
{
    __shared__ float As[16][68];
    __shared__ float Bs[16][68];

    const int tid = threadIdx.x;
    const int tx = tid & 15, ty = tid >> 4;
    const int mbase = blockIdx.x * 64;
    const int nbase = blockIdx.y * 64;

    const int lr  = tid >> 2;
    const int lq  = tid & 3;
    const int lkk = tid >> 4;
    const int lj  = tid & 15;

    const int arow = mbase + lr;
    const int ab = arow >> 11, an = arow & (NN - 1);

    float acc[4][4] = {};

    for (int k0 = 0; k0 < EMB; k0 += 16) {
        const int e = k0 + lq * 4;           // head-merged column, multiple of 4
        const int h = e / HD, d = e % HD;    // never crosses a 96 boundary
        float4 a = *(const float4*)&AO[(((size_t)(ab * HEADS + h)) * NN + an) * HD + d];
        float4 b = *(const float4*)&Wo[(size_t)(k0 + lkk) * EMB + nbase + lj * 4];
        __syncthreads();
        As[lq*4+0][lr] = a.x; As[lq*4+1][lr] = a.y;
        As[lq*4+2][lr] = a.z; As[lq*4+3][lr] = a.w;
        *(float4*)&Bs[lkk][lj*4] = b;
        __syncthreads();
        #pragma unroll
        for (int kk = 0; kk < 16; ++kk) {
            float4 av = *(const float4*)&As[kk][ty*4];
            float4 bv4 = *(const float4*)&Bs[kk][tx*4];
            float am[4] = {av.x, av.y, av.z, av.w};
            float bm[4] = {bv4.x, bv4.y, bv4.z, bv4.w};
            #pragma unroll
            for (int i = 0; i < 4; ++i)
                #pragma unroll
                for (int j = 0; j < 4; ++j)
                    acc[i][j] += am[i] * bm[j];
        }
    }

    #pragma unroll
    for (int i = 0; i < 4; ++i) {
        const int row = mbase + ty*4 + i;
        #pragma unroll
        for (int j = 0; j < 4; ++j) {
            const int e = nbase + tx*4 + j;
            out[(size_t)row * EMB + e] = acc[i][j] + bo[e];
        }
    }
}

// ---------------------------------------------------------------------------
extern "C" void kernel_launch(void* const* d_in, const int* in_sizes, int n_in,
                              void* d_out, int out_size, void* d_ws, size_t ws_size,
                              hipStream_t stream)
{
    const float* x  = (const float*)d_in[0];
    const float* Wq = (const float*)d_in[1];
    const float* bq = (const float*)d_in[2];
    const float* Wk = (const float*)d_in[3];
    const float* bk = (const float*)d_in[4];
    const float* Wv = (const float*)d_in[5];
    const float* bv = (const float*)d_in[6];
    const float* Wo = (const float*)d_in[7];
    const float* bo = (const float*)d_in[8];

    float* ws = (float*)d_ws;
    const size_t SZ = (size_t)BN * EMB;   // 6,291,456 floats
    float* Q  = ws;
    float* K  = Q + SZ;
    float* V  = K + SZ;
    float* AO = V + SZ;

    dim3 g1(BN / 64, EMB / 64, 3);
    proj_qkv<<<g1, 256, 0, stream>>>(x, Wq, bq, Wk, bk, Wv, bv, Q, K, V);

    dim3 g2(NN / 32, BB * HEADS);
    attn_fwd<<<g2, 256, 0, stream>>>(Q, K, V, AO);

    dim3 g3(BN / 64, EMB / 64);
    proj_out_k<<<g3, 256, 0, stream>>>(AO, Wo, bo, (float*)d_out);
}

// Round 3
// 208.205 us; speedup vs baseline: 6.9172x; 6.9172x over previous
//
#include <hip/hip_runtime.h>

typedef _Float16 half_t;
typedef __attribute__((ext_vector_type(8))) _Float16 half8;
typedef __attribute__((ext_vector_type(4))) float f32x4;

#define EMB 768
#define HEADS 8
#define HD 96
#define BB 4
#define NN 2048
#define BN (BB*NN)   // 8192

static __device__ __forceinline__ f32x4 mfma16(half8 a, half8 b, f32x4 c) {
    return __builtin_amdgcn_mfma_f32_16x16x32_f16(a, b, c, 0, 0, 0);
}

// ---------------------------------------------------------------------------
// fp32 -> f16 (element count multiple of 4; one float4 per thread)
// ---------------------------------------------------------------------------
__global__ void cvt_f32_f16(const float* __restrict__ in, half_t* __restrict__ out, int n4) {
    int i = blockIdx.x * blockDim.x + threadIdx.x;
    if (i < n4) {
        float4 v = ((const float4*)in)[i];
        union { half_t h[4]; uint2 u; } t;
        t.h[0] = (half_t)v.x; t.h[1] = (half_t)v.y;
        t.h[2] = (half_t)v.z; t.h[3] = (half_t)v.w;
        ((uint2*)out)[i] = t.u;
    }
}

// ---------------------------------------------------------------------------
// W[768][768] fp32 -> WT[768][768] f16 (transposed). grid (24,24,4), block 256.
// ---------------------------------------------------------------------------
__global__ __launch_bounds__(256) void cvt_transpose_w(
    const float* __restrict__ W0, const float* __restrict__ W1,
    const float* __restrict__ W2, const float* __restrict__ W3,
    half_t* __restrict__ T0, half_t* __restrict__ T1,
    half_t* __restrict__ T2, half_t* __restrict__ T3)
{
    const float* W; half_t* T;
    switch (blockIdx.z) {
        case 0: W = W0; T = T0; break;
        case 1: W = W1; T = T1; break;
        case 2: W = W2; T = T2; break;
        default: W = W3; T = T3; break;
    }
    __shared__ float ls[32][33];
    const int k0 = blockIdx.x * 32, n0 = blockIdx.y * 32;
    const int r = threadIdx.x >> 3, c4 = (threadIdx.x & 7) * 4;
    float4 v = *(const float4*)&W[(size_t)(k0 + r) * EMB + n0 + c4];
    ls[r][c4+0] = v.x; ls[r][c4+1] = v.y; ls[r][c4+2] = v.z; ls[r][c4+3] = v.w;
    __syncthreads();
    union { half_t h[4]; uint2 u; } t;
    #pragma unroll
    for (int j = 0; j < 4; ++j) t.h[j] = (half_t)ls[c4 + j][r];
    *(uint2*)&T[(size_t)(n0 + r) * EMB + k0 + c4] = t.u;
}

// ---------------------------------------------------------------------------
// QKV projection, f16 MFMA. C = x @ W + b. 128x128 tile, BK=32, 4 waves.
// Q,K written [bh][n][96]; V written transposed [bh][96][n].
// grid (64, 6, 3), block 256.
// ---------------------------------------------------------------------------
__global__ __launch_bounds__(256) void proj_qkv_h(
    const half_t* __restrict__ xh,
    const half_t* __restrict__ WqT, const float* __restrict__ bq,
    const half_t* __restrict__ WkT, const float* __restrict__ bk,
    const half_t* __restrict__ WvT, const float* __restrict__ bv,
    half_t* __restrict__ Qo, half_t* __restrict__ Ko, half_t* __restrict__ Vt)
{
    const half_t* WT; const float* bias;
    const int z = blockIdx.z;
    if (z == 0)      { WT = WqT; bias = bq; }
    else if (z == 1) { WT = WkT; bias = bk; }
    else             { WT = WvT; bias = bv; }

    __shared__ half_t As[128][56];   // row stride 112B: 16B-aligned, conflict-free b128
    __shared__ half_t Bs[128][56];

    const int tid = threadIdx.x;
    const int lane = tid & 63;
    const int wid = tid >> 6;
    const int lr = lane & 15;
    const int lkg = lane >> 4;
    const int wm = (wid >> 1) * 64;
    const int wn = (wid & 1) * 64;
    const int mbase = blockIdx.x * 128;
    const int nbase = blockIdx.y * 128;

    const int srr = tid >> 2;        // 0..63
    const int skk = (tid & 3) * 8;   // 0,8,16,24

    f32x4 acc[4][4];
    const f32x4 z4 = {0.f, 0.f, 0.f, 0.f};
    #pragma unroll
    for (int i = 0; i < 4; ++i)
        #pragma unroll
        for (int j = 0; j < 4; ++j) acc[i][j] = z4;

    const half_t* aptr = xh + (size_t)(mbase + srr) * EMB + skk;
    const half_t* bptr = WT + (size_t)(nbase + srr) * EMB + skk;

    half8 a0 = *(const half8*)aptr;
    half8 a1 = *(const half8*)(aptr + 64 * EMB);
    half8 b0 = *(const half8*)bptr;
    half8 b1 = *(const half8*)(bptr + 64 * EMB);

    for (int k0 = 0; k0 < EMB; k0 += 32) {
        __syncthreads();
        *(half8*)&As[srr][skk]      = a0;
        *(half8*)&As[srr + 64][skk] = a1;
        *(half8*)&Bs[srr][skk]      = b0;
        *(half8*)&Bs[srr + 64][skk] = b1;
        __syncthreads();
        if (k0 + 32 < EMB) {
            a0 = *(const half8*)(aptr + k0 + 32);
            a1 = *(const half8*)(aptr + k0 + 32 + 64 * EMB);
            b0 = *(const half8*)(bptr + k0 + 32);
            b1 = *(const half8*)(bptr + k0 + 32 + 64 * EMB);
        }
        half8 af[4], bf[4];
        #pragma unroll
        for (int mi = 0; mi < 4; ++mi)
            af[mi] = *(const half8*)&As[wm + mi*16 + lr][lkg*8];
        #pragma unroll
        for (int ni = 0; ni < 4; ++ni)
            bf[ni] = *(const half8*)&Bs[wn + ni*16 + lr][lkg*8];
        #pragma unroll
        for (int mi = 0; mi < 4; ++mi)
            #pragma unroll
            for (int ni = 0; ni < 4; ++ni)
                acc[mi][ni] = mfma16(af[mi], bf[ni], acc[mi][ni]);
    }

    // epilogue: C/D layout col = lane&15, row = (lane>>4)*4 + reg
    #pragma unroll
    for (int ni = 0; ni < 4; ++ni) {
        const int e = nbase + wn + ni*16 + lr;
        const float be = bias[e];
        const int h = e / HD, d = e % HD;
        #pragma unroll
        for (int mi = 0; mi < 4; ++mi) {
            const int row0 = mbase + wm + mi*16 + lkg*4;
            const int b = row0 >> 11, n0 = row0 & (NN - 1);
            if (z == 2) {
                union { half_t hh[4]; uint2 u; } t;
                #pragma unroll
                for (int r = 0; r < 4; ++r) t.hh[r] = (half_t)(acc[mi][ni][r] + be);
                *(uint2*)&Vt[((size_t)(b*HEADS + h) * HD + d) * NN + n0] = t.u;
            } else {
                half_t* outp = (z == 0) ? Qo : Ko;
                #pragma unroll
                for (int r = 0; r < 4; ++r)
                    outp[((size_t)(b*HEADS + h) * NN + n0 + r) * HD + d] =
                        (half_t)(acc[mi][ni][r] + be);
            }
        }
    }
}

// ---------------------------------------------------------------------------
// Flash attention, f16 MFMA. QBLK=128 (4 waves x 32 rows), KVBLK=64.
// softmax on unscaled logits; /sqrt(96) post-softmax folded into epilogue.
// grid (16, 32), block 256.
// ---------------------------------------------------------------------------
__global__ __launch_bounds__(256) void attn_h(
    const half_t* __restrict__ Qh, const half_t* __restrict__ Kh,
    const half_t* __restrict__ Vth, half_t* __restrict__ AOh)
{
    __shared__ __align__(16) char smem[45568];
    half_t* Qs = (half_t*)smem;             // [128][104] (prologue only)
    half_t* Ks = (half_t*)smem;             // [64][104]  = 13312 B
    half_t* Vs = (half_t*)(smem + 13312);   // [96][72]   = 13824 B
    half_t* Ps = (half_t*)(smem + 27136);   // [4][32][72]= 18432 B

    const int tid = threadIdx.x;
    const int lane = tid & 63;
    const int wid = tid >> 6;
    const int lr = lane & 15;
    const int lkg = lane >> 4;
    const int wq = wid * 32;
    const int qbase = blockIdx.x * 128;
    const int bh = blockIdx.y;

    const half_t* Qp = Qh + (size_t)bh * NN * HD;
    const half_t* Kp = Kh + (size_t)bh * NN * HD;
    const half_t* Vp = Vth + (size_t)bh * HD * NN;
    half_t* AOp = AOh + (size_t)bh * NN * HD;

    // stage Q tile 128x96: 256 threads x 48-half segment = 6 x half8
    {
        const int r = tid >> 1, hf = (tid & 1) * 48;
        const half_t* src = Qp + (size_t)(qbase + r) * HD + hf;
        #pragma unroll
        for (int c = 0; c < 6; ++c) {
            half8 q = *(const half8*)(src + c * 8);
            *(half8*)&Qs[r*104 + hf + c * 8] = q;
        }
    }
    __syncthreads();
    half8 qf[2][3];
    #pragma unroll
    for (int mi = 0; mi < 2; ++mi)
        #pragma unroll
        for (int kg = 0; kg < 3; ++kg)
            qf[mi][kg] = *(const half8*)&Qs[(wq + mi*16 + lr)*104 + kg*32 + lkg*8];
    __syncthreads();   // Qs region free for K/V staging

    f32x4 o[2][6];
    const f32x4 z4 = {0.f, 0.f, 0.f, 0.f};
    #pragma unroll
    for (int mi = 0; mi < 2; ++mi)
        #pragma unroll
        for (int nf = 0; nf < 6; ++nf) o[mi][nf] = z4;
    float mreg[2][4], lreg[2][4];
    #pragma unroll
    for (int mi = 0; mi < 2; ++mi)
        #pragma unroll
        for (int r = 0; r < 4; ++r) { mreg[mi][r] = -1e30f; lreg[mi][r] = 0.f; }

    const int kr = tid >> 2, ks4 = (tid & 3) * 24;   // K stage: row, 24-half seg = 3 x half8
    const int vd = tid >> 1, vh = (tid & 1) * 32;    // V stage: d-row, 32-half half = 4 x half8

    // preload tile 0
    half8 kva, kvb, kvc, vv0, vv1, vv2, vv3;
    {
        const half_t* ksrc = Kp + (size_t)kr * HD + ks4;
        kva = *(const half8*)(ksrc);
        kvb = *(const half8*)(ksrc + 8);
        kvc = *(const half8*)(ksrc + 16);
        if (tid < 192) {
            const half_t* vsrc = Vp + (size_t)vd * NN + vh;
            vv0 = *(const half8*)(vsrc);      vv1 = *(const half8*)(vsrc + 8);
            vv2 = *(const half8*)(vsrc + 16); vv3 = *(const half8*)(vsrc + 24);
        }
    }

    half_t* Psw = Ps + wid * 32 * 72;

    for (int kt = 0; kt < NN / 64; ++kt) {
        // write staged tile
        *(half8*)&Ks[kr*104 + ks4]      = kva;
        *(half8*)&Ks[kr*104 + ks4 + 8]  = kvb;
        *(half8*)&Ks[kr*104 + ks4 + 16] = kvc;
        if (tid < 192) {
            *(half8*)&Vs[vd*72 + vh]      = vv0;
            *(half8*)&Vs[vd*72 + vh + 8]  = vv1;
            *(half8*)&Vs[vd*72 + vh + 16] = vv2;
            *(half8*)&Vs[vd*72 + vh + 24] = vv3;
        }
        __syncthreads();
        // prefetch next tile (overlaps compute)
        if (kt + 1 < NN / 64) {
            const int kb = (kt + 1) * 64;
            const half_t* ksrc = Kp + (size_t)(kb + kr) * HD + ks4;
            kva = *(const half8*)(ksrc);
            kvb = *(const half8*)(ksrc + 8);
            kvc = *(const half8*)(ksrc + 16);
            if (tid < 192) {
                const half_t* vsrc = Vp + (size_t)vd * NN + kb + vh;
                vv0 = *(const half8*)(vsrc);      vv1 = *(const half8*)(vsrc + 8);
                vv2 = *(const half8*)(vsrc + 16); vv3 = *(const half8*)(vsrc + 24);
            }
        }

        // S = Q K^T  (per wave: 32 x 64, K=96)
        f32x4 s[2][4];
        #pragma unroll
        for (int mi = 0; mi < 2; ++mi)
            #pragma unroll
            for (int ni = 0; ni < 4; ++ni) s[mi][ni] = z4;
        #pragma unroll
        for (int ni = 0; ni < 4; ++ni)
            #pragma unroll
            for (int kg = 0; kg < 3; ++kg) {
                half8 kf = *(const half8*)&Ks[(ni*16 + lr)*104 + kg*32 + lkg*8];
                s[0][ni] = mfma16(qf[0][kg], kf, s[0][ni]);
                s[1][ni] = mfma16(qf[1][kg], kf, s[1][ni]);
            }

        // online softmax (row = (lane>>4)*4+reg; reduce over lane&15 x 4 ni)
        float scv[2][4];
        #pragma unroll
        for (int mi = 0; mi < 2; ++mi)
            #pragma unroll
            for (int r = 0; r < 4; ++r) {
                float tm = fmaxf(fmaxf(s[mi][0][r], s[mi][1][r]),
                                 fmaxf(s[mi][2][r], s[mi][3][r]));
                tm = fmaxf(tm, __shfl_xor(tm, 1));
                tm = fmaxf(tm, __shfl_xor(tm, 2));
                tm = fmaxf(tm, __shfl_xor(tm, 4));
                tm = fmaxf(tm, __shfl_xor(tm, 8));
                const float mn = fmaxf(mreg[mi][r], tm);
                const float sc = __expf(mreg[mi][r] - mn);
                mreg[mi][r] = mn;
                scv[mi][r] = sc;
                float rs = 0.f;
                #pragma unroll
                for (int ni = 0; ni < 4; ++ni) {
                    const float p = __expf(s[mi][ni][r] - mn);
                    s[mi][ni][r] = p;
                    rs += p;
                }
                rs += __shfl_xor(rs, 1);
                rs += __shfl_xor(rs, 2);
                rs += __shfl_xor(rs, 4);
                rs += __shfl_xor(rs, 8);
                lreg[mi][r] = lreg[mi][r] * sc + rs;
            }

        // stage P (C-layout -> A-layout via per-wave LDS), rescale O
        #pragma unroll
        for (int mi = 0; mi < 2; ++mi)
            #pragma unroll
            for (int ni = 0; ni < 4; ++ni)
                #pragma unroll
                for (int r = 0; r < 4; ++r)
                    Psw[(mi*16 + lkg*4 + r)*72 + ni*16 + lr] = (half_t)s[mi][ni][r];
        #pragma unroll
        for (int mi = 0; mi < 2; ++mi)
            #pragma unroll
            for (int nf = 0; nf < 6; ++nf)
                #pragma unroll
                for (int r = 0; r < 4; ++r)
                    o[mi][nf][r] *= scv[mi][r];

        // O += P @ V   (B from Vt tile: Vs[d][key])
        #pragma unroll
        for (int ks = 0; ks < 2; ++ks) {
            half8 pa0 = *(const half8*)&Psw[(lr)*72      + ks*32 + lkg*8];
            half8 pa1 = *(const half8*)&Psw[(16 + lr)*72 + ks*32 + lkg*8];
            #pragma unroll
            for (int nf = 0; nf < 6; ++nf) {
                half8 vf = *(const half8*)&Vs[(nf*16 + lr)*72 + ks*32 + lkg*8];
                o[0][nf] = mfma16(pa0, vf, o[0][nf]);
                o[1][nf] = mfma16(pa1, vf, o[1][nf]);
            }
        }
        __syncthreads();   // compute reads done before next iteration's writes
    }

    // epilogue: O * (1/l) * 1/sqrt(96), store f16 [bh][n][96]
    const float isq = 0.10206207261596577f;
    #pragma unroll
    for (int mi = 0; mi < 2; ++mi)
        #pragma unroll
        for (int r = 0; r < 4; ++r) {
            const float inv = isq / lreg[mi][r];
            const int row = qbase + wq + mi*16 + lkg*4 + r;
            #pragma unroll
            for (int nf = 0; nf < 6; ++nf)
                AOp[(size_t)row * HD + nf*16 + lr] = (half_t)(o[mi][nf][r] * inv);
        }
}

// ---------------------------------------------------------------------------
// Output projection: out(fp32) = AO(head-split f16) @ WoT + bo.
// grid (64, 6), block 256.
// ---------------------------------------------------------------------------
__global__ __launch_bounds__(256) void proj_out_h(
    const half_t* __restrict__ AOh, const half_t* __restrict__ WoT,
    const float* __restrict__ bo, float* __restrict__ out)
{
    __shared__ half_t As[128][56];
    __shared__ half_t Bs[128][56];

    const int tid = threadIdx.x;
    const int lane = tid & 63;
    const int wid = tid >> 6;
    const int lr = lane & 15;
    const int lkg = lane >> 4;
    const int wm = (wid >> 1) * 64;
    const int wn = (wid & 1) * 64;
    const int mbase = blockIdx.x * 128;
    const int nbase = blockIdx.y * 128;

    const int srr = tid >> 2;
    const int skk = (tid & 3) * 8;

    const int arow0 = mbase + srr;
    const int ab0 = arow0 >> 11, an0 = arow0 & (NN - 1);
    const int arow1 = arow0 + 64;
    const int ab1 = arow1 >> 11, an1 = arow1 & (NN - 1);

    f32x4 acc[4][4];
    const f32x4 z4 = {0.f, 0.f, 0.f, 0.f};
    #pragma unroll
    for (int i = 0; i < 4; ++i)
        #pragma unroll
        for (int j = 0; j < 4; ++j) acc[i][j] = z4;

    const half_t* bptr = WoT + (size_t)(nbase + srr) * EMB + skk;

    // A gather: e = k0 + skk -> head h = k0/96 (BK=32 never crosses a 96 boundary)
#define ALOAD(b_, n_, k0_) \
    (*(const half8*)&AOh[((size_t)((b_)*HEADS + (k0_)/HD) * NN + (n_)) * HD + ((k0_)%HD) + skk])

    half8 a0 = ALOAD(ab0, an0, 0);
    half8 a1 = ALOAD(ab1, an1, 0);
    half8 b0 = *(const half8*)bptr;
    half8 b1 = *(const half8*)(bptr + 64 * EMB);

    for (int k0 = 0; k0 < EMB; k0 += 32) {
        __syncthreads();
        *(half8*)&As[srr][skk]      = a0;
        *(half8*)&As[srr + 64][skk] = a1;
        *(half8*)&Bs[srr][skk]      = b0;
        *(half8*)&Bs[srr + 64][skk] = b1;
        __syncthreads();
        if (k0 + 32 < EMB) {
            const int kn = k0 + 32;
            a0 = ALOAD(ab0, an0, kn);
            a1 = ALOAD(ab1, an1, kn);
            b0 = *(const half8*)(bptr + kn);
            b1 = *(const half8*)(bptr + kn + 64 * EMB);
        }
        half8 af[4], bf[4];
        #pragma unroll
        for (int mi = 0; mi < 4; ++mi)
            af[mi] = *(const half8*)&As[wm + mi*16 + lr][lkg*8];
        #pragma unroll
        for (int ni = 0; ni < 4; ++ni)
            bf[ni] = *(const half8*)&Bs[wn + ni*16 + lr][lkg*8];
        #pragma unroll
        for (int mi = 0; mi < 4; ++mi)
            #pragma unroll
            for (int ni = 0; ni < 4; ++ni)
                acc[mi][ni] = mfma16(af[mi], bf[ni], acc[mi][ni]);
    }
#undef ALOAD

    #pragma unroll
    for (int ni = 0; ni < 4; ++ni) {
        const int e = nbase + wn + ni*16 + lr;
        const float be = bo[e];
        #pragma unroll
        for (int mi = 0; mi < 4; ++mi) {
            const int row0 = mbase + wm + mi*16 + lkg*4;
            #pragma unroll
            for (int r = 0; r < 4; ++r)
                out[(size_t)(row0 + r) * EMB + e] = acc[mi][ni][r] + be;
        }
    }
}

// ---------------------------------------------------------------------------
extern "C" void kernel_launch(void* const* d_in, const int* in_sizes, int n_in,
                              void* d_out, int out_size, void* d_ws, size_t ws_size,
                              hipStream_t stream)
{
    const float* x  = (const float*)d_in[0];
    const float* Wq = (const float*)d_in[1];
    const float* bq = (const float*)d_in[2];
    const float* Wk = (const float*)d_in[3];
    const float* bk = (const float*)d_in[4];
    const float* Wv = (const float*)d_in[5];
    const float* bv = (const float*)d_in[6];
    const float* Wo = (const float*)d_in[7];
    const float* bo = (const float*)d_in[8];

    const size_t SZ = (size_t)BN * EMB;   // 6,291,456
    const size_t WS = (size_t)EMB * EMB;  //   589,824

    half_t* ws  = (half_t*)d_ws;
    half_t* xh  = ws;
    half_t* WqT = xh  + SZ;
    half_t* WkT = WqT + WS;
    half_t* WvT = WkT + WS;
    half_t* WoT = WvT + WS;
    half_t* Qh  = WoT + WS;
    half_t* Kh  = Qh  + SZ;
    half_t* Vth = Kh  + SZ;
    half_t* AOh = Vth + SZ;

    // x -> f16
    cvt_f32_f16<<<(int)(SZ / 4 / 256), 256, 0, stream>>>(x, xh, (int)(SZ / 4));
    // weights -> f16 transposed
    cvt_transpose_w<<<dim3(EMB/32, EMB/32, 4), 256, 0, stream>>>(
        Wq, Wk, Wv, Wo, WqT, WkT, WvT, WoT);

    // QKV projection (V transposed on write)
    proj_qkv_h<<<dim3(BN/128, EMB/128, 3), 256, 0, stream>>>(
        xh, WqT, bq, WkT, bk, WvT, bv, Qh, Kh, Vth);

    // attention
    attn_h<<<dim3(NN/128, BB*HEADS), 256, 0, stream>>>(Qh, Kh, Vth, AOh);

    // output projection
    proj_out_h<<<dim3(BN/128, EMB/128), 256, 0, stream>>>(AOh, WoT, bo, (float*)d_out);
}

// Round 5
// 169.931 us; speedup vs baseline: 8.4752x; 1.2252x over previous
//
#include <hip/hip_runtime.h>

typedef _Float16 half_t;
typedef __attribute__((ext_vector_type(8))) _Float16 half8;
typedef __attribute__((ext_vector_type(2))) __fp16 fp16x2;
typedef __attribute__((ext_vector_type(4))) float f32x4;
typedef __attribute__((ext_vector_type(16))) float f32x16;

#define EMB 768
#define HEADS 8
#define HD 96
#define BB 4
#define NN 2048
#define BN (BB*NN)   // 8192

static __device__ __forceinline__ f32x4 mfma16(half8 a, half8 b, f32x4 c) {
    return __builtin_amdgcn_mfma_f32_16x16x32_f16(a, b, c, 0, 0, 0);
}
static __device__ __forceinline__ f32x16 mfma32(half8 a, half8 b, f32x16 c) {
    return __builtin_amdgcn_mfma_f32_32x32x16_f16(a, b, c, 0, 0, 0);
}
static __device__ __forceinline__ unsigned pkrtz(float a, float b) {
    fp16x2 h = __builtin_amdgcn_cvt_pkrtz(a, b);
    return __builtin_bit_cast(unsigned, h);
}
static __device__ __forceinline__ unsigned sx32(unsigned v) {
    return (unsigned)__shfl_xor((int)v, 32);
}

// ---------------------------------------------------------------------------
// fp32 -> f16
// ---------------------------------------------------------------------------
__global__ void cvt_f32_f16(const float* __restrict__ in, half_t* __restrict__ out, int n4) {
    int i = blockIdx.x * blockDim.x + threadIdx.x;
    if (i < n4) {
        float4 v = ((const float4*)in)[i];
        union { half_t h[4]; uint2 u; } t;
        t.h[0] = (half_t)v.x; t.h[1] = (half_t)v.y;
        t.h[2] = (half_t)v.z; t.h[3] = (half_t)v.w;
        ((uint2*)out)[i] = t.u;
    }
}

// ---------------------------------------------------------------------------
// W[768][768] fp32 -> WT[768][768] f16 (transposed). grid (24,24,4), block 256.
// ---------------------------------------------------------------------------
__global__ __launch_bounds__(256) void cvt_transpose_w(
    const float* __restrict__ W0, const float* __restrict__ W1,
    const float* __restrict__ W2, const float* __restrict__ W3,
    half_t* __restrict__ T0, half_t* __restrict__ T1,
    half_t* __restrict__ T2, half_t* __restrict__ T3)
{
    const float* W; half_t* T;
    switch (blockIdx.z) {
        case 0: W = W0; T = T0; break;
        case 1: W = W1; T = T1; break;
        case 2: W = W2; T = T2; break;
        default: W = W3; T = T3; break;
    }
    __shared__ float ls[32][33];
    const int k0 = blockIdx.x * 32, n0 = blockIdx.y * 32;
    const int r = threadIdx.x >> 3, c4 = (threadIdx.x & 7) * 4;
    float4 v = *(const float4*)&W[(size_t)(k0 + r) * EMB + n0 + c4];
    ls[r][c4+0] = v.x; ls[r][c4+1] = v.y; ls[r][c4+2] = v.z; ls[r][c4+3] = v.w;
    __syncthreads();
    union { half_t h[4]; uint2 u; } t;
    #pragma unroll
    for (int j = 0; j < 4; ++j) t.h[j] = (half_t)ls[c4 + j][r];
    *(uint2*)&T[(size_t)(n0 + r) * EMB + k0 + c4] = t.u;
}

// ---------------------------------------------------------------------------
// QKV projection, f16 MFMA. 128x128 tile, BK=32, 4 waves.
// Q (scaled by log2e), K written [bh][n][96]; V written transposed [bh][96][n].
// ---------------------------------------------------------------------------
__global__ __launch_bounds__(256) void proj_qkv_h(
    const half_t* __restrict__ xh,
    const half_t* __restrict__ WqT, const float* __restrict__ bq,
    const half_t* __restrict__ WkT, const float* __restrict__ bk,
    const half_t* __restrict__ WvT, const float* __restrict__ bv,
    half_t* __restrict__ Qo, half_t* __restrict__ Ko, half_t* __restrict__ Vt)
{
    const half_t* WT; const float* bias;
    const int z = blockIdx.z;
    if (z == 0)      { WT = WqT; bias = bq; }
    else if (z == 1) { WT = WkT; bias = bk; }
    else             { WT = WvT; bias = bv; }

    __shared__ half_t As[128][56];
    __shared__ half_t Bs[128][56];

    const int tid = threadIdx.x;
    const int lane = tid & 63;
    const int wid = tid >> 6;
    const int lr = lane & 15;
    const int lkg = lane >> 4;
    const int wm = (wid >> 1) * 64;
    const int wn = (wid & 1) * 64;
    const int mbase = blockIdx.x * 128;
    const int nbase = blockIdx.y * 128;

    const int srr = tid >> 2;
    const int skk = (tid & 3) * 8;

    f32x4 acc[4][4];
    const f32x4 z4 = {0.f, 0.f, 0.f, 0.f};
    #pragma unroll
    for (int i = 0; i < 4; ++i)
        #pragma unroll
        for (int j = 0; j < 4; ++j) acc[i][j] = z4;

    const half_t* aptr = xh + (size_t)(mbase + srr) * EMB + skk;
    const half_t* bptr = WT + (size_t)(nbase + srr) * EMB + skk;

    half8 a0 = *(const half8*)aptr;
    half8 a1 = *(const half8*)(aptr + 64 * EMB);
    half8 b0 = *(const half8*)bptr;
    half8 b1 = *(const half8*)(bptr + 64 * EMB);

    for (int k0 = 0; k0 < EMB; k0 += 32) {
        __syncthreads();
        *(half8*)&As[srr][skk]      = a0;
        *(half8*)&As[srr + 64][skk] = a1;
        *(half8*)&Bs[srr][skk]      = b0;
        *(half8*)&Bs[srr + 64][skk] = b1;
        __syncthreads();
        if (k0 + 32 < EMB) {
            a0 = *(const half8*)(aptr + k0 + 32);
            a1 = *(const half8*)(aptr + k0 + 32 + 64 * EMB);
            b0 = *(const half8*)(bptr + k0 + 32);
            b1 = *(const half8*)(bptr + k0 + 32 + 64 * EMB);
        }
        half8 af[4], bf[4];
        #pragma unroll
        for (int mi = 0; mi < 4; ++mi)
            af[mi] = *(const half8*)&As[wm + mi*16 + lr][lkg*8];
        #pragma unroll
        for (int ni = 0; ni < 4; ++ni)
            bf[ni] = *(const half8*)&Bs[wn + ni*16 + lr][lkg*8];
        #pragma unroll
        for (int mi = 0; mi < 4; ++mi)
            #pragma unroll
            for (int ni = 0; ni < 4; ++ni)
                acc[mi][ni] = mfma16(af[mi], bf[ni], acc[mi][ni]);
    }

    // Q gets pre-scaled by log2(e): softmax(s)=softmax(s*log2e) via exp2
    const float qscale = (z == 0) ? 1.4426950408889634f : 1.0f;

    #pragma unroll
    for (int ni = 0; ni < 4; ++ni) {
        const int e = nbase + wn + ni*16 + lr;
        const float be = bias[e];
        const int h = e / HD, d = e % HD;
        #pragma unroll
        for (int mi = 0; mi < 4; ++mi) {
            const int row0 = mbase + wm + mi*16 + lkg*4;
            const int b = row0 >> 11, n0 = row0 & (NN - 1);
            if (z == 2) {
                union { half_t hh[4]; uint2 u; } t;
                #pragma unroll
                for (int r = 0; r < 4; ++r) t.hh[r] = (half_t)(acc[mi][ni][r] + be);
                *(uint2*)&Vt[((size_t)(b*HEADS + h) * HD + d) * NN + n0] = t.u;
            } else {
                half_t* outp = (z == 0) ? Qo : Ko;
                #pragma unroll
                for (int r = 0; r < 4; ++r)
                    outp[((size_t)(b*HEADS + h) * NN + n0 + r) * HD + d] =
                        (half_t)((acc[mi][ni][r] + be) * qscale);
            }
        }
    }
}

// ---------------------------------------------------------------------------
// Flash attention v2: 32x32x16 MFMA, both GEMMs operand-swapped.
// S^T = mfma(K, Q): lane owns q = lane&31; reductions 1 shfl.
// O^T = mfma(V^T, P^T): P stays in-register (cvt_pkrtz + shfl_xor(32)).
// Defer-max (THR=8, log2 domain). K/V LDS XOR-swizzled, 24.5 KB total.
// grid (16, 32), block 256 (4 waves x 32 q-rows).
// ---------------------------------------------------------------------------
__global__ __launch_bounds__(256, 3) void attn_h(
    const half_t* __restrict__ Qh, const half_t* __restrict__ Kh,
    const half_t* __restrict__ Vth, half_t* __restrict__ AOh)
{
    __shared__ __align__(16) char smem[24576];
    // Qs[128][96] (prologue, overlays everything)
    // Ks[64][96] at 0 (12288 B), Vs[96][64] at 12288 (12288 B); all swizzled

    const int tid = threadIdx.x;
    const int lane = tid & 63;
    const int wid = tid >> 6;
    const int l31 = lane & 31;
    const int b5 = lane >> 5;
    const int wq = wid * 32;
    const int qbase = blockIdx.x * 128;
    const int bh = blockIdx.y;

    const half_t* Qp = Qh + (size_t)bh * NN * HD;
    const half_t* Kp = Kh + (size_t)bh * NN * HD;
    const half_t* Vp = Vth + (size_t)bh * HD * NN;
    half_t* AOp = AOh + (size_t)bh * NN * HD;

    // ---- preload K/V tile 0 into regs (issue early) ----
    const int kr = tid >> 2;               // K row 0..63
    const int kcb = (tid & 3) * 48;        // K col byte 0/48/96/144
    const int vd = tid >> 1;               // V row 0..95 (tid<192)
    const int vcb = (tid & 1) * 64;        // V col byte 0/64
    half8 kv0, kv1, kv2, vv0, vv1, vv2, vv3;
    {
        const half_t* ksrc = Kp + (size_t)kr * HD + kcb / 2;
        kv0 = *(const half8*)(ksrc);
        kv1 = *(const half8*)(ksrc + 8);
        kv2 = *(const half8*)(ksrc + 16);
        if (tid < 192) {
            const half_t* vsrc = Vp + (size_t)vd * NN + vcb / 2;
            vv0 = *(const half8*)(vsrc);      vv1 = *(const half8*)(vsrc + 8);
            vv2 = *(const half8*)(vsrc + 16); vv3 = *(const half8*)(vsrc + 24);
        }
    }

    // ---- stage Q [128][96] swizzled, read B-frags, release LDS ----
    {
        const int r = tid >> 1;
        const int cb = (tid & 1) * 96;
        const half_t* src = Qp + (size_t)(qbase + r) * HD + cb / 2;
        #pragma unroll
        for (int c = 0; c < 6; ++c) {
            half8 q = *(const half8*)(src + c * 8);
            *(half8*)(smem + ((r * 192 + cb + c * 16) ^ ((r & 7) << 4))) = q;
        }
    }
    __syncthreads();
    half8 qf[6];
    {
        const int r = wq + l31;
        #pragma unroll
        for (int kg = 0; kg < 6; ++kg)
            qf[kg] = *(const half8*)(smem + ((r * 192 + kg * 32 + 16 * b5) ^ ((r & 7) << 4)));
    }
    __syncthreads();

    // ---- state ----
    f32x16 acc[3];
    const f32x16 z16 = {0.f,0.f,0.f,0.f,0.f,0.f,0.f,0.f,0.f,0.f,0.f,0.f,0.f,0.f,0.f,0.f};
    acc[0] = z16; acc[1] = z16; acc[2] = z16;
    float mreg = -1e30f, lreg = 0.f;

    for (int kt = 0; kt < NN / 64; ++kt) {
        // write staged K/V tile (swizzled)
        {
            *(half8*)((char*)smem + ((kr * 192 + kcb +  0) ^ ((kr & 7) << 4))) = kv0;
            *(half8*)((char*)smem + ((kr * 192 + kcb + 16) ^ ((kr & 7) << 4))) = kv1;
            *(half8*)((char*)smem + ((kr * 192 + kcb + 32) ^ ((kr & 7) << 4))) = kv2;
            if (tid < 192) {
                char* vb = smem + 12288;
                *(half8*)(vb + ((vd * 128 + vcb +  0) ^ ((vd & 7) << 4))) = vv0;
                *(half8*)(vb + ((vd * 128 + vcb + 16) ^ ((vd & 7) << 4))) = vv1;
                *(half8*)(vb + ((vd * 128 + vcb + 32) ^ ((vd & 7) << 4))) = vv2;
                *(half8*)(vb + ((vd * 128 + vcb + 48) ^ ((vd & 7) << 4))) = vv3;
            }
        }
        __syncthreads();

        // prefetch next tile
        if (kt + 1 < NN / 64) {
            const int kb = (kt + 1) * 64;
            const half_t* ksrc = Kp + (size_t)(kb + kr) * HD + kcb / 2;
            kv0 = *(const half8*)(ksrc);
            kv1 = *(const half8*)(ksrc + 8);
            kv2 = *(const half8*)(ksrc + 16);
            if (tid < 192) {
                const half_t* vsrc = Vp + (size_t)vd * NN + kb + vcb / 2;
                vv0 = *(const half8*)(vsrc);      vv1 = *(const half8*)(vsrc + 8);
                vv2 = *(const half8*)(vsrc + 16); vv3 = *(const half8*)(vsrc + 24);
            }
        }

        // two 32-kv subtiles
        #pragma unroll
        for (int tile = 0; tile < 2; ++tile) {
            // S^T[kv][q] = sum_d K[kv][d] * Q[q][d]
            f32x16 st = z16;
            #pragma unroll
            for (int kg = 0; kg < 6; ++kg) {
                const int kv = tile * 32 + l31;
                half8 kf = *(const half8*)(smem +
                    ((kv * 192 + kg * 32 + 16 * b5) ^ ((kv & 7) << 4)));
                st = mfma32(kf, qf[kg], st);
            }

            // row max over this lane's 16 kv + partner's 16
            float tm = st[0];
            #pragma unroll
            for (int i = 1; i < 16; ++i) tm = fmaxf(tm, st[i]);
            tm = fmaxf(tm, __shfl_xor(tm, 32));

            // defer-max: rescale only when tile max exceeds running max + 8
            if (!__all(tm <= mreg + 8.0f)) {
                const float mn = fmaxf(mreg, tm);
                const float sc = exp2f(mreg - mn);
                lreg *= sc;
                #pragma unroll
                for (int db = 0; db < 3; ++db)
                    #pragma unroll
                    for (int i = 0; i < 16; ++i) acc[db][i] *= sc;
                mreg = mn;
            }

            // P = exp2(S^T - m), row sum
            float rs = 0.f;
            #pragma unroll
            for (int i = 0; i < 16; ++i) {
                const float p = exp2f(st[i] - mreg);
                st[i] = p;
                rs += p;
            }
            rs += __shfl_xor(rs, 32);
            lreg += rs;

            // pack P quads to f16 (kv = r + 8*rr + 4*b5, q = l31)
            unsigned pk[4][2];
            #pragma unroll
            for (int rr = 0; rr < 4; ++rr) {
                pk[rr][0] = pkrtz(st[rr*4+0], st[rr*4+1]);
                pk[rr][1] = pkrtz(st[rr*4+2], st[rr*4+3]);
            }

            // build P^T B-frags via b5-partner exchange, accumulate O^T
            #pragma unroll
            for (int ks = 0; ks < 2; ++ks) {
                const unsigned z0 = b5 ? pk[2*ks][0] : pk[2*ks+1][0];
                const unsigned z1 = b5 ? pk[2*ks][1] : pk[2*ks+1][1];
                const unsigned x0 = sx32(z0);
                const unsigned x1 = sx32(z1);
                union { unsigned u[4]; half8 h; } afu;
                afu.u[0] = b5 ? x0 : pk[2*ks][0];
                afu.u[1] = b5 ? x1 : pk[2*ks][1];
                afu.u[2] = b5 ? pk[2*ks+1][0] : x0;
                afu.u[3] = b5 ? pk[2*ks+1][1] : x1;
                const half8 af = afu.h;
                #pragma unroll
                for (int db = 0; db < 3; ++db) {
                    const int d = db * 32 + l31;
                    half8 vf = *(const half8*)(smem + 12288 +
                        ((d * 128 + tile * 64 + ks * 32 + 16 * b5) ^ ((d & 7) << 4)));
                    acc[db] = mfma32(vf, af, acc[db]);
                }
            }
        }
        __syncthreads();
    }

    // epilogue: O = O^T normalized; lane owns q = l31. /sqrt(96) post-softmax.
    const float isq = 0.10206207261596577f;
    const float inv = isq / lreg;
    const int q = qbase + wq + l31;
    half_t* dst = AOp + (size_t)q * HD;
    #pragma unroll
    for (int db = 0; db < 3; ++db)
        #pragma unroll
        for (int rr = 0; rr < 4; ++rr) {
            const int d0 = db * 32 + rr * 8 + 4 * b5;
            union { half_t h[4]; uint2 u; } t;
            #pragma unroll
            for (int r = 0; r < 4; ++r)
                t.h[r] = (half_t)(acc[db][rr*4 + r] * inv);
            *(uint2*)&dst[d0] = t.u;
        }
}

// ---------------------------------------------------------------------------
// Output projection: out(fp32) = AO(head-split f16) @ WoT + bo.
// ---------------------------------------------------------------------------
__global__ __launch_bounds__(256) void proj_out_h(
    const half_t* __restrict__ AOh, const half_t* __restrict__ WoT,
    const float* __restrict__ bo, float* __restrict__ out)
{
    __shared__ half_t As[128][56];
    __shared__ half_t Bs[128][56];

    const int tid = threadIdx.x;
    const int lane = tid & 63;
    const int wid = tid >> 6;
    const int lr = lane & 15;
    const int lkg = lane >> 4;
    const int wm = (wid >> 1) * 64;
    const int wn = (wid & 1) * 64;
    const int mbase = blockIdx.x * 128;
    const int nbase = blockIdx.y * 128;

    const int srr = tid >> 2;
    const int skk = (tid & 3) * 8;

    const int arow0 = mbase + srr;
    const int ab0 = arow0 >> 11, an0 = arow0 & (NN - 1);
    const int arow1 = arow0 + 64;
    const int ab1 = arow1 >> 11, an1 = arow1 & (NN - 1);

    f32x4 acc[4][4];
    const f32x4 z4 = {0.f, 0.f, 0.f, 0.f};
    #pragma unroll
    for (int i = 0; i < 4; ++i)
        #pragma unroll
        for (int j = 0; j < 4; ++j) acc[i][j] = z4;

    const half_t* bptr = WoT + (size_t)(nbase + srr) * EMB + skk;

#define ALOAD(b_, n_, k0_) \
    (*(const half8*)&AOh[((size_t)((b_)*HEADS + (k0_)/HD) * NN + (n_)) * HD + ((k0_)%HD) + skk])

    half8 a0 = ALOAD(ab0, an0, 0);
    half8 a1 = ALOAD(ab1, an1, 0);
    half8 b0 = *(const half8*)bptr;
    half8 b1 = *(const half8*)(bptr + 64 * EMB);

    for (int k0 = 0; k0 < EMB; k0 += 32) {
        __syncthreads();
        *(half8*)&As[srr][skk]      = a0;
        *(half8*)&As[srr + 64][skk] = a1;
        *(half8*)&Bs[srr][skk]      = b0;
        *(half8*)&Bs[srr + 64][skk] = b1;
        __syncthreads();
        if (k0 + 32 < EMB) {
            const int kn = k0 + 32;
            a0 = ALOAD(ab0, an0, kn);
            a1 = ALOAD(ab1, an1, kn);
            b0 = *(const half8*)(bptr + kn);
            b1 = *(const half8*)(bptr + kn + 64 * EMB);
        }
        half8 af[4], bf[4];
        #pragma unroll
        for (int mi = 0; mi < 4; ++mi)
            af[mi] = *(const half8*)&As[wm + mi*16 + lr][lkg*8];
        #pragma unroll
        for (int ni = 0; ni < 4; ++ni)
            bf[ni] = *(const half8*)&Bs[wn + ni*16 + lr][lkg*8];
        #pragma unroll
        for (int mi = 0; mi < 4; ++mi)
            #pragma unroll
            for (int ni = 0; ni < 4; ++ni)
                acc[mi][ni] = mfma16(af[mi], bf[ni], acc[mi][ni]);
    }
#undef ALOAD

    #pragma unroll
    for (int ni = 0; ni < 4; ++ni) {
        const int e = nbase + wn + ni*16 + lr;
        const float be = bo[e];
        #pragma unroll
        for (int mi = 0; mi < 4; ++mi) {
            const int row0 = mbase + wm + mi*16 + lkg*4;
            #pragma unroll
            for (int r = 0; r < 4; ++r)
                out[(size_t)(row0 + r) * EMB + e] = acc[mi][ni][r] + be;
        }
    }
}

// ---------------------------------------------------------------------------
extern "C" void kernel_launch(void* const* d_in, const int* in_sizes, int n_in,
                              void* d_out, int out_size, void* d_ws, size_t ws_size,
                              hipStream_t stream)
{
    const float* x  = (const float*)d_in[0];
    const float* Wq = (const float*)d_in[1];
    const float* bq = (const float*)d_in[2];
    const float* Wk = (const float*)d_in[3];
    const float* bk = (const float*)d_in[4];
    const float* Wv = (const float*)d_in[5];
    const float* bv = (const float*)d_in[6];
    const float* Wo = (const float*)d_in[7];
    const float* bo = (const float*)d_in[8];

    const size_t SZ = (size_t)BN * EMB;   // 6,291,456
    const size_t WS = (size_t)EMB * EMB;  //   589,824

    half_t* ws  = (half_t*)d_ws;
    half_t* xh  = ws;
    half_t* WqT = xh  + SZ;
    half_t* WkT = WqT + WS;
    half_t* WvT = WkT + WS;
    half_t* WoT = WvT + WS;
    half_t* Qh  = WoT + WS;
    half_t* Kh  = Qh  + SZ;
    half_t* Vth = Kh  + SZ;
    half_t* AOh = Vth + SZ;

    cvt_f32_f16<<<(int)(SZ / 4 / 256), 256, 0, stream>>>(x, xh, (int)(SZ / 4));
    cvt_transpose_w<<<dim3(EMB/32, EMB/32, 4), 256, 0, stream>>>(
        Wq, Wk, Wv, Wo, WqT, WkT, WvT, WoT);

    proj_qkv_h<<<dim3(BN/128, EMB/128, 3), 256, 0, stream>>>(
        xh, WqT, bq, WkT, bk, WvT, bv, Qh, Kh, Vth);

    attn_h<<<dim3(NN/128, BB*HEADS), 256, 0, stream>>>(Qh, Kh, Vth, AOh);

    proj_out_h<<<dim3(BN/128, EMB/128), 256, 0, stream>>>(AOh, WoT, bo, (float*)d_out);
}